// Round 4
// baseline (372.269 us; speedup 1.0000x reference)
//
#include <hip/hip_runtime.h>
#include <stdint.h>

typedef __bf16 bf16;
typedef __bf16 bf16x8 __attribute__((ext_vector_type(8)));
typedef __bf16 bf16x4 __attribute__((ext_vector_type(4)));
typedef float f32x4 __attribute__((ext_vector_type(4)));

#define DEV static __device__ __forceinline__

// ---------------------------------------------------------------------------
// async global->LDS, 16B per lane. LDS dest is wave-uniform base + lane*16.
// ---------------------------------------------------------------------------
DEV void async_copy16(const bf16* gsrc, const bf16* ldst) {
  __builtin_amdgcn_global_load_lds(
      (__attribute__((address_space(1))) void*)(uintptr_t)gsrc,
      (__attribute__((address_space(3))) void*)(uint32_t)(uintptr_t)ldst,
      16, 0, 0);
}

// ---------------------------------------------------------------------------
// Shared 128x128 (BK=64) bf16 MFMA GEMM mainloop, C = A * B^T.
// A: [M,K] row-major (lda), B: [N,K] row-major (ldb). 256 threads, 4 waves
// in 2x2 grid; each wave owns 64x64 = 4x4 MFMA 16x16x32 tiles.
// NOTE (R3 post-mortem): 32x32x16 MFMA regressed — its fragment read has 4
// lanes on identical swizzled segments (8.5e6 bank conflicts, +5 µs). The
// 16x16x32 pattern below staggers segments per k-quad: measured 0 conflicts.
//
// LDS XOR swizzle (verified 0 conflicts in R2): row stride is 64 elem = 32
// banks; we permute 16B colsegs by (row&7). Staging thread t loads GLOBAL
// colseg (t&7)^(row&7) into its fixed lane-contiguous LDS slot, so
// LDS[row, s] = global[row, s^(row&7)]; readers xor element offset with
// (row&7)*8.
// ---------------------------------------------------------------------------
DEV void gemm_tile(const bf16* __restrict__ A, const bf16* __restrict__ B,
                   int lda, int ldb, int kTiles,
                   bf16* As, bf16* Bs, f32x4 acc[4][4]) {
  const int tid  = threadIdx.x;
  const int wave = tid >> 6;
  const int lane = tid & 63;
  const int wm = (wave >> 1) * 64;   // wave row base in tile
  const int wn = (wave & 1) * 64;    // wave col base in tile
  const int mf = lane & 15;          // fragment row within 16
  const int jb = lane >> 4;          // k-quad 0..3
  const int sw = (mf & 7) * 8;       // xor for swizzled element offset

  // staging: thread t covers row (t>>3) (+i*32), swizzled colseg
  const int srow = tid >> 3;
  const int scol = ((tid & 7) ^ (srow & 7)) * 8;
  const bf16* Ag = A + (size_t)srow * lda + scol;
  const bf16* Bg = B + (size_t)srow * ldb + scol;
  bf16* Asw = As + wave * 512;  // wave-uniform LDS base (elements)
  bf16* Bsw = Bs + wave * 512;

  for (int kt = 0; kt < kTiles; ++kt) {
    __syncthreads();  // previous iter's LDS reads done before overwrite
    const bf16* ag = Ag + kt * 64;
    const bf16* bg = Bg + kt * 64;
#pragma unroll
    for (int i = 0; i < 4; ++i) {
      async_copy16(ag + (size_t)(i * 32) * lda, Asw + i * 2048);
      async_copy16(bg + (size_t)(i * 32) * ldb, Bsw + i * 2048);
    }
    __syncthreads();  // compiler emits vmcnt(0) drain before barrier
#pragma unroll
    for (int ks = 0; ks < 2; ++ks) {
      const int j8 = (ks * 4 + jb) * 8;   // un-swizzled element offset in row
      bf16x8 af[4], bv[4];
#pragma unroll
      for (int i = 0; i < 4; ++i)
        af[i] = *(const bf16x8*)&As[(wm + i * 16 + mf) * 64 + (j8 ^ sw)];
#pragma unroll
      for (int j = 0; j < 4; ++j)
        bv[j] = *(const bf16x8*)&Bs[(wn + j * 16 + mf) * 64 + (j8 ^ sw)];
#pragma unroll
      for (int i = 0; i < 4; ++i)
#pragma unroll
        for (int j = 0; j < 4; ++j)
          acc[i][j] = __builtin_amdgcn_mfma_f32_16x16x32_bf16(af[i], bv[j], acc[i][j], 0, 0, 0);
    }
  }
}

// C/D layout (verified m89/m91): col = lane&15, row = (lane>>4)*4 + reg.

// ---------------------------------------------------------------------------
// Kernel 1: merged cast — x (16.78M floats) then Wq|Wk|Wv (3.15M floats),
// 4 floats/thread. One launch instead of two.
// ---------------------------------------------------------------------------
__global__ __launch_bounds__(256) void k_cast_all(const float* __restrict__ X,
                                                  const float* __restrict__ Wq,
                                                  const float* __restrict__ Wk,
                                                  const float* __restrict__ Wv,
                                                  bf16* __restrict__ Xb,
                                                  bf16* __restrict__ Wb) {
  int i = blockIdx.x * 256 + threadIdx.x;  // float4 index, 4980736 total
  const float* src;
  bf16* dst;
  int off;
  if (i < 4194304) {            // x
    src = X; dst = Xb; off = i;
  } else {                      // weights, 262144 float4 per matrix
    int j = i - 4194304;
    int which = j >> 18;
    src = (which == 0) ? Wq : ((which == 1) ? Wk : Wv);
    dst = Wb + (size_t)(j >> 18) * 1048576;
    off = j & 262143;
  }
  float4 v = ((const float4*)src)[off];
  bf16x4 o = {(bf16)v.x, (bf16)v.y, (bf16)v.z, (bf16)v.w};
  ((bf16x4*)dst)[off] = o;
}

// ---------------------------------------------------------------------------
// Epilogue helper: store wave's 4x4 16x16 fp32 tiles.
// ---------------------------------------------------------------------------
#define EPILOGUE(STMT)                                                       \
  do {                                                                       \
    const int lane = threadIdx.x & 63, wave = threadIdx.x >> 6;              \
    const int colb = n0 + (wave & 1) * 64 + (lane & 15);                     \
    const int rowb = m0 + (wave >> 1) * 64 + (lane >> 4) * 4;                \
    _Pragma("unroll") for (int i = 0; i < 4; ++i)                            \
      _Pragma("unroll") for (int r = 0; r < 4; ++r) {                        \
        size_t row = rowb + i * 16 + r;                                      \
        _Pragma("unroll") for (int j = 0; j < 4; ++j) {                      \
          size_t col = colb + j * 16;                                        \
          float val = acc[i][j][r];                                          \
          STMT;                                                              \
        }                                                                    \
      }                                                                      \
  } while (0)

// ---------------------------------------------------------------------------
// Kernel 2: QKV = Xb @ Wb^T  (M=16384, N=3072, K=1024), bf16 out, ldc=3072.
// Q columns are pre-scaled by 1/32 = 1/sqrt(D) (exact exponent shift in
// bf16) so the scores epilogue stores raw. K/V rows beyond lens[b] skipped.
// ---------------------------------------------------------------------------
__global__ __launch_bounds__(256) void k_gemm_qkv(const bf16* __restrict__ X,
                                                  const bf16* __restrict__ W,
                                                  const int* __restrict__ lens,
                                                  bf16* __restrict__ QKV) {
  const int n0 = blockIdx.x * 128;
  const int m0 = blockIdx.y * 128;
  if (n0 >= 1024 && (m0 & 2047) >= lens[m0 >> 11]) return;  // block-uniform
  __shared__ __align__(16) bf16 As[128 * 64];
  __shared__ __align__(16) bf16 Bs[128 * 64];
  f32x4 acc[4][4] = {};
  gemm_tile(X + (size_t)m0 * 1024, W + (size_t)n0 * 1024, 1024, 1024, 16, As, Bs, acc);
  const float qscale = (n0 < 1024) ? 0.03125f : 1.0f;  // block-uniform
  EPILOGUE(QKV[row * 3072 + col] = (bf16)(val * qscale));
}

// ---------------------------------------------------------------------------
// Kernel 3: transpose V part of QKV -> Vt[b][d][s]. Skip s-blocks >= kmax
// (out-GEMM reads only s < ceil64(len); P there is exactly 0, poison finite).
// ---------------------------------------------------------------------------
__global__ __launch_bounds__(256) void k_transpose_v(const bf16* __restrict__ QKV,
                                                     const int* __restrict__ lens,
                                                     bf16* __restrict__ Vt) {
  __shared__ bf16 tile[32][33];
  const int b = blockIdx.z;
  const int s0 = blockIdx.x * 32;
  if (s0 >= ((lens[b] + 63) & ~63)) return;
  const int d0 = blockIdx.y * 32;
  const int tx = threadIdx.x, ty = threadIdx.y;  // (32, 8)
#pragma unroll
  for (int i = 0; i < 4; ++i)
    tile[ty + i * 8][tx] = QKV[(size_t)(b * 2048 + s0 + ty + i * 8) * 3072 + 2048 + d0 + tx];
  __syncthreads();
#pragma unroll
  for (int i = 0; i < 4; ++i)
    Vt[(size_t)(b * 1024 + d0 + ty + i * 8) * 2048 + s0 + tx] = tile[tx][ty + i * 8];
}

// ---------------------------------------------------------------------------
// Kernel 4: S = Q @ K^T per batch (Q pre-scaled), bf16 out. Skip key-tiles
// >= len (softmax never reads them).
// ---------------------------------------------------------------------------
__global__ __launch_bounds__(256) void k_gemm_scores(const bf16* __restrict__ QKV,
                                                     const int* __restrict__ lens,
                                                     bf16* __restrict__ S) {
  const int b = blockIdx.z;
  const int len = lens[b];
  const int n0 = blockIdx.x * 128;  // key tile
  if (n0 >= len) return;            // uniform per block — safe w.r.t. barriers
  const int m0 = blockIdx.y * 128;  // query tile
  __shared__ __align__(16) bf16 As[128 * 64];
  __shared__ __align__(16) bf16 Bs[128 * 64];
  const bf16* Q = QKV + (size_t)b * 2048 * 3072;
  const bf16* K = Q + 1024;
  f32x4 acc[4][4] = {};
  gemm_tile(Q + (size_t)m0 * 3072, K + (size_t)n0 * 3072, 3072, 3072, 16, As, Bs, acc);
  bf16* Sb = S + (size_t)b * 2048 * 2048;
  EPILOGUE(Sb[row * 2048 + col] = (bf16)val);
}

// ---------------------------------------------------------------------------
// Kernel 5: masked softmax per row, in place (S -> P). One pass: 2048 cols /
// 256 threads = one bf16x8 per thread in registers. Loads/stores only chunks
// that matter: loads below len, stores below kmax = ceil64(len) with zeros
// on [len, kmax) (out-GEMM reads nothing beyond kmax).
// ---------------------------------------------------------------------------
__global__ __launch_bounds__(256) void k_softmax(bf16* __restrict__ S,
                                                 const int* __restrict__ lens) {
  const int row = blockIdx.x;  // 0..16383 (= b*2048 + q)
  const int len = lens[row >> 11];
  const int kmax = (len + 63) & ~63;
  bf16* Sr = S + (size_t)row * 2048;
  const int tid = threadIdx.x;
  const int base = tid * 8;
  __shared__ float red[4];

  float f[8];
  if (base < len) {
    bf16x8 v = ((const bf16x8*)Sr)[tid];
#pragma unroll
    for (int e = 0; e < 8; ++e) f[e] = (base + e < len) ? (float)v[e] : -1e30f;
  } else {
#pragma unroll
    for (int e = 0; e < 8; ++e) f[e] = -1e30f;
  }
  float m = -1e30f;
#pragma unroll
  for (int e = 0; e < 8; ++e) m = fmaxf(m, f[e]);
#pragma unroll
  for (int off = 32; off; off >>= 1) m = fmaxf(m, __shfl_xor(m, off));
  if ((tid & 63) == 0) red[tid >> 6] = m;
  __syncthreads();
  m = fmaxf(fmaxf(red[0], red[1]), fmaxf(red[2], red[3]));
  __syncthreads();  // all reads of red done before reuse

  float s = 0.f;
#pragma unroll
  for (int e = 0; e < 8; ++e) {
    float p = (base + e < len) ? __expf(f[e] - m) : 0.f;
    f[e] = p;
    s += p;
  }
#pragma unroll
  for (int off = 32; off; off >>= 1) s += __shfl_xor(s, off);
  if ((tid & 63) == 0) red[tid >> 6] = s;
  __syncthreads();
  s = red[0] + red[1] + red[2] + red[3];
  const float inv = 1.f / s;

  if (base < kmax) {
    bf16x8 o;
#pragma unroll
    for (int e = 0; e < 8; ++e) o[e] = (bf16)(f[e] * inv);
    ((bf16x8*)Sr)[tid] = o;
  }
}

// ---------------------------------------------------------------------------
// Kernel 6: O = P @ Vt^T per batch (M=2048, N=1024, K=ceil(len,64)), fp32 out
// ---------------------------------------------------------------------------
__global__ __launch_bounds__(256) void k_gemm_out(const bf16* __restrict__ P,
                                                  const bf16* __restrict__ Vt,
                                                  const int* __restrict__ lens,
                                                  float* __restrict__ Out) {
  const int b = blockIdx.z;
  const int kTiles = (lens[b] + 63) >> 6;  // P is zero beyond len within tile
  const int n0 = blockIdx.x * 128;  // over d (1024)
  const int m0 = blockIdx.y * 128;  // over queries
  __shared__ __align__(16) bf16 As[128 * 64];
  __shared__ __align__(16) bf16 Bs[128 * 64];
  const bf16* Pb = P + (size_t)b * 2048 * 2048;
  const bf16* Vb = Vt + (size_t)b * 1024 * 2048;
  f32x4 acc[4][4] = {};
  gemm_tile(Pb + (size_t)m0 * 2048, Vb + (size_t)n0 * 2048, 2048, 2048, kTiles, As, Bs, acc);
  float* Ob = Out + (size_t)b * 2048 * 1024;
  EPILOGUE(Ob[row * 1024 + col] = val);
}

// ---------------------------------------------------------------------------
// Workspace layout (bytes):
//   [0,   32M)   Xb   (dead after GEMM1)  \ overlapped by
//   [32M, 38M)   Wb   (dead after GEMM1)  /  S/P: [0, 64M)
//   [64M, 160M)  QKV  bf16 [16384][3072]
//   [160M,192M)  Vt   bf16 [8][1024][2048]
// ---------------------------------------------------------------------------
extern "C" void kernel_launch(void* const* d_in, const int* in_sizes, int n_in,
                              void* d_out, int out_size, void* d_ws, size_t ws_size,
                              hipStream_t stream) {
  const float* x   = (const float*)d_in[0];
  const int* lens  = (const int*)d_in[1];
  const float* Wq  = (const float*)d_in[2];
  const float* Wk  = (const float*)d_in[3];
  const float* Wv  = (const float*)d_in[4];
  float* out = (float*)d_out;

  char* ws = (char*)d_ws;
  bf16* S   = (bf16*)(ws);                 // 64 MiB (scores, then P in place)
  bf16* Xb  = (bf16*)(ws);                 // 32 MiB, overlaps S (dead first)
  bf16* Wb  = (bf16*)(ws + 33554432);      // 6 MiB, overlaps S
  bf16* QKV = (bf16*)(ws + 67108864);      // 96 MiB
  bf16* Vt  = (bf16*)(ws + 167772160);     // 32 MiB

  k_cast_all<<<19456, 256, 0, stream>>>(x, Wq, Wk, Wv, Xb, Wb);
  k_gemm_qkv<<<dim3(24, 128), 256, 0, stream>>>(Xb, Wb, lens, QKV);
  k_transpose_v<<<dim3(64, 32, 8), dim3(32, 8), 0, stream>>>(QKV, lens, Vt);
  k_gemm_scores<<<dim3(16, 16, 8), 256, 0, stream>>>(QKV, lens, S);
  k_softmax<<<16384, 256, 0, stream>>>(S, lens);
  k_gemm_out<<<dim3(8, 16, 8), 256, 0, stream>>>(S, Vt, lens, out);
}

// Round 5
// 355.882 us; speedup vs baseline: 1.0460x; 1.0460x over previous
//
#include <hip/hip_runtime.h>
#include <stdint.h>

typedef __bf16 bf16;
typedef __bf16 bf16x8 __attribute__((ext_vector_type(8)));
typedef __bf16 bf16x4 __attribute__((ext_vector_type(4)));
typedef float f32x4 __attribute__((ext_vector_type(4)));
typedef float f32x16 __attribute__((ext_vector_type(16)));

#define DEV static __device__ __forceinline__

// ---------------------------------------------------------------------------
// async global->LDS, 16B per lane. LDS dest is wave-uniform base + lane*16.
// ---------------------------------------------------------------------------
DEV void async_copy16(const bf16* gsrc, const bf16* ldst) {
  __builtin_amdgcn_global_load_lds(
      (__attribute__((address_space(1))) void*)(uintptr_t)gsrc,
      (__attribute__((address_space(3))) void*)(uint32_t)(uintptr_t)ldst,
      16, 0, 0);
}

// ---------------------------------------------------------------------------
// 128x128 (BK=64) bf16 MFMA GEMM mainloops, C = A * B^T.
// A: [M,K] row-major (lda), B: [N,K] row-major (ldb). 256 threads, 4 waves
// in 2x2 grid; each wave owns a 64x64 subtile.
//
// LDS XOR swizzle (verified 0-conflict for the 16x16 read in R2): row stride
// 64 elem = exactly 32 banks; we permute 16B colsegs by (row&7). Staging
// thread t loads GLOBAL colseg (t&7)^(row&7) into its fixed lane-contiguous
// slot, so LDS[row, s] = global[row, s^(row&7)]; readers xor their element
// offset with (row&7)*8.
//
// MFMA shape choice is PER-KERNEL, measurement-driven (R3/R4 A/B):
//  - 16x16x32 variant: 0 bank conflicts; best where the loop is
//    staging/barrier-bound (qkv: HBM-heavy fetch).   [R2: qkv 88 µs]
//  - 32x32x16 variant: ~17% fewer MFMA-pipe cyc/kt (m119) but ~8.5e6 bank
//    conflicts; best where staging hits L2 and the MFMA pipe is critical
//    (scores/out: per-batch working sets reused).    [R3: total -20 µs]
// ---------------------------------------------------------------------------
DEV void gemm_tile16(const bf16* __restrict__ A, const bf16* __restrict__ B,
                     int lda, int ldb, int kTiles,
                     bf16* As, bf16* Bs, f32x4 acc[4][4]) {
  const int tid  = threadIdx.x;
  const int wave = tid >> 6;
  const int lane = tid & 63;
  const int wm = (wave >> 1) * 64;
  const int wn = (wave & 1) * 64;
  const int mf = lane & 15;          // fragment row within 16
  const int jb = lane >> 4;          // k-quad 0..3
  const int sw = (mf & 7) * 8;       // xor for swizzled element offset

  const int srow = tid >> 3;
  const int scol = ((tid & 7) ^ (srow & 7)) * 8;
  const bf16* Ag = A + (size_t)srow * lda + scol;
  const bf16* Bg = B + (size_t)srow * ldb + scol;
  bf16* Asw = As + wave * 512;
  bf16* Bsw = Bs + wave * 512;

  for (int kt = 0; kt < kTiles; ++kt) {
    __syncthreads();
    const bf16* ag = Ag + kt * 64;
    const bf16* bg = Bg + kt * 64;
#pragma unroll
    for (int i = 0; i < 4; ++i) {
      async_copy16(ag + (size_t)(i * 32) * lda, Asw + i * 2048);
      async_copy16(bg + (size_t)(i * 32) * ldb, Bsw + i * 2048);
    }
    __syncthreads();
#pragma unroll
    for (int ks = 0; ks < 2; ++ks) {
      const int j8 = (ks * 4 + jb) * 8;
      bf16x8 af[4], bv[4];
#pragma unroll
      for (int i = 0; i < 4; ++i)
        af[i] = *(const bf16x8*)&As[(wm + i * 16 + mf) * 64 + (j8 ^ sw)];
#pragma unroll
      for (int j = 0; j < 4; ++j)
        bv[j] = *(const bf16x8*)&Bs[(wn + j * 16 + mf) * 64 + (j8 ^ sw)];
#pragma unroll
      for (int i = 0; i < 4; ++i)
#pragma unroll
        for (int j = 0; j < 4; ++j)
          acc[i][j] = __builtin_amdgcn_mfma_f32_16x16x32_bf16(af[i], bv[j], acc[i][j], 0, 0, 0);
    }
  }
}

DEV void gemm_tile32(const bf16* __restrict__ A, const bf16* __restrict__ B,
                     int lda, int ldb, int kTiles,
                     bf16* As, bf16* Bs, f32x16 acc[2][2]) {
  const int tid  = threadIdx.x;
  const int wave = tid >> 6;
  const int lane = tid & 63;
  const int wm = (wave >> 1) * 64;
  const int wn = (wave & 1) * 64;
  const int rf = lane & 31;          // fragment row (m/n) within 32
  const int kh = (lane >> 5) * 8;    // k-half offset within 16
  const int sw = (lane & 7) * 8;     // xor for swizzled element offset

  const int srow = tid >> 3;
  const int scol = ((tid & 7) ^ (srow & 7)) * 8;
  const bf16* Ag = A + (size_t)srow * lda + scol;
  const bf16* Bg = B + (size_t)srow * ldb + scol;
  bf16* Asw = As + wave * 512;
  bf16* Bsw = Bs + wave * 512;

  for (int kt = 0; kt < kTiles; ++kt) {
    __syncthreads();
    const bf16* ag = Ag + kt * 64;
    const bf16* bg = Bg + kt * 64;
#pragma unroll
    for (int i = 0; i < 4; ++i) {
      async_copy16(ag + (size_t)(i * 32) * lda, Asw + i * 2048);
      async_copy16(bg + (size_t)(i * 32) * ldb, Bsw + i * 2048);
    }
    __syncthreads();
#pragma unroll
    for (int ks = 0; ks < 4; ++ks) {
      const int off = (ks * 16 + kh) ^ sw;
      bf16x8 a0 = *(const bf16x8*)&As[(wm + rf) * 64 + off];
      bf16x8 a1 = *(const bf16x8*)&As[(wm + 32 + rf) * 64 + off];
      bf16x8 b0 = *(const bf16x8*)&Bs[(wn + rf) * 64 + off];
      bf16x8 b1 = *(const bf16x8*)&Bs[(wn + 32 + rf) * 64 + off];
      acc[0][0] = __builtin_amdgcn_mfma_f32_32x32x16_bf16(a0, b0, acc[0][0], 0, 0, 0);
      acc[0][1] = __builtin_amdgcn_mfma_f32_32x32x16_bf16(a0, b1, acc[0][1], 0, 0, 0);
      acc[1][0] = __builtin_amdgcn_mfma_f32_32x32x16_bf16(a1, b0, acc[1][0], 0, 0, 0);
      acc[1][1] = __builtin_amdgcn_mfma_f32_32x32x16_bf16(a1, b1, acc[1][1], 0, 0, 0);
    }
  }
}

// ---------------------------------------------------------------------------
// Epilogues. 16x16 C/D (m89/m91): col=lane&15, row=(lane>>4)*4+reg.
// 32x32 C/D (m74/m101): col=lane&31, row=(reg&3)+8*(reg>>2)+4*(lane>>5).
// ---------------------------------------------------------------------------
#define EPILOGUE16(STMT)                                                     \
  do {                                                                       \
    const int lane = threadIdx.x & 63, wave = threadIdx.x >> 6;              \
    const int colb = n0 + (wave & 1) * 64 + (lane & 15);                     \
    const int rowb = m0 + (wave >> 1) * 64 + (lane >> 4) * 4;                \
    _Pragma("unroll") for (int i = 0; i < 4; ++i)                            \
      _Pragma("unroll") for (int r = 0; r < 4; ++r) {                        \
        size_t row = rowb + i * 16 + r;                                      \
        _Pragma("unroll") for (int j = 0; j < 4; ++j) {                      \
          size_t col = colb + j * 16;                                        \
          float val = acc[i][j][r];                                          \
          STMT;                                                              \
        }                                                                    \
      }                                                                      \
  } while (0)

#define EPILOGUE32(STMT)                                                     \
  do {                                                                       \
    const int lane = threadIdx.x & 63, wave = threadIdx.x >> 6;              \
    const int colb = n0 + (wave & 1) * 64 + (lane & 31);                     \
    const int rowb = m0 + (wave >> 1) * 64 + (lane >> 5) * 4;                \
    _Pragma("unroll") for (int i = 0; i < 2; ++i)                            \
      _Pragma("unroll") for (int reg = 0; reg < 16; ++reg) {                 \
        size_t row = rowb + i * 32 + (reg & 3) + 8 * (reg >> 2);             \
        _Pragma("unroll") for (int j = 0; j < 2; ++j) {                      \
          size_t col = colb + j * 32;                                        \
          float val = acc[i][j][reg];                                        \
          STMT;                                                              \
        }                                                                    \
      }                                                                      \
  } while (0)

// ---------------------------------------------------------------------------
// Kernel 1: merged cast — x (16.78M floats) then Wq|Wk|Wv (3.15M floats).
// ---------------------------------------------------------------------------
__global__ __launch_bounds__(256) void k_cast_all(const float* __restrict__ X,
                                                  const float* __restrict__ Wq,
                                                  const float* __restrict__ Wk,
                                                  const float* __restrict__ Wv,
                                                  bf16* __restrict__ Xb,
                                                  bf16* __restrict__ Wb) {
  int i = blockIdx.x * 256 + threadIdx.x;  // float4 index, 4980736 total
  const float* src;
  bf16* dst;
  int off;
  if (i < 4194304) {            // x
    src = X; dst = Xb; off = i;
  } else {                      // weights, 262144 float4 per matrix
    int j = i - 4194304;
    int which = j >> 18;
    src = (which == 0) ? Wq : ((which == 1) ? Wk : Wv);
    dst = Wb + (size_t)(j >> 18) * 1048576;
    off = j & 262143;
  }
  float4 v = ((const float4*)src)[off];
  bf16x4 o = {(bf16)v.x, (bf16)v.y, (bf16)v.z, (bf16)v.w};
  ((bf16x4*)dst)[off] = o;
}

// ---------------------------------------------------------------------------
// Kernel 2: QKV = Xb @ Wb^T (M=16384, N=3072, K=1024), bf16, ldc=3072.
// 16x16x32 path (0 bank conflicts; this kernel is staging/HBM-bound).
// Q pre-scaled by 1/32 (exact exponent shift). K/V rows beyond lens skipped.
// ---------------------------------------------------------------------------
__global__ __launch_bounds__(256) void k_gemm_qkv(const bf16* __restrict__ X,
                                                  const bf16* __restrict__ W,
                                                  const int* __restrict__ lens,
                                                  bf16* __restrict__ QKV) {
  const int n0 = blockIdx.x * 128;
  const int m0 = blockIdx.y * 128;
  if (n0 >= 1024 && (m0 & 2047) >= lens[m0 >> 11]) return;  // block-uniform
  __shared__ __align__(16) bf16 As[128 * 64];
  __shared__ __align__(16) bf16 Bs[128 * 64];
  f32x4 acc[4][4] = {};
  gemm_tile16(X + (size_t)m0 * 1024, W + (size_t)n0 * 1024, 1024, 1024, 16, As, Bs, acc);
  const float qscale = (n0 < 1024) ? 0.03125f : 1.0f;  // block-uniform
  EPILOGUE16(QKV[row * 3072 + col] = (bf16)(val * qscale));
}

// ---------------------------------------------------------------------------
// Kernel 3: transpose V part of QKV -> Vt[b][d][s]. Skip s-blocks >= kmax.
// ---------------------------------------------------------------------------
__global__ __launch_bounds__(256) void k_transpose_v(const bf16* __restrict__ QKV,
                                                     const int* __restrict__ lens,
                                                     bf16* __restrict__ Vt) {
  __shared__ bf16 tile[32][33];
  const int b = blockIdx.z;
  const int s0 = blockIdx.x * 32;
  if (s0 >= ((lens[b] + 63) & ~63)) return;
  const int d0 = blockIdx.y * 32;
  const int tx = threadIdx.x, ty = threadIdx.y;  // (32, 8)
#pragma unroll
  for (int i = 0; i < 4; ++i)
    tile[ty + i * 8][tx] = QKV[(size_t)(b * 2048 + s0 + ty + i * 8) * 3072 + 2048 + d0 + tx];
  __syncthreads();
#pragma unroll
  for (int i = 0; i < 4; ++i)
    Vt[(size_t)(b * 1024 + d0 + ty + i * 8) * 2048 + s0 + tx] = tile[tx][ty + i * 8];
}

// ---------------------------------------------------------------------------
// Kernel 4: S = Q @ K^T per batch (Q pre-scaled), bf16. 32x32x16 path
// (L2-resident staging -> MFMA-pipe-bound; R3 measured win). Skip >= len.
// ---------------------------------------------------------------------------
__global__ __launch_bounds__(256) void k_gemm_scores(const bf16* __restrict__ QKV,
                                                     const int* __restrict__ lens,
                                                     bf16* __restrict__ S) {
  const int b = blockIdx.z;
  const int len = lens[b];
  const int n0 = blockIdx.x * 128;  // key tile
  if (n0 >= len) return;            // uniform per block
  const int m0 = blockIdx.y * 128;  // query tile
  __shared__ __align__(16) bf16 As[128 * 64];
  __shared__ __align__(16) bf16 Bs[128 * 64];
  const bf16* Q = QKV + (size_t)b * 2048 * 3072;
  const bf16* K = Q + 1024;
  f32x16 acc[2][2] = {};
  gemm_tile32(Q + (size_t)m0 * 3072, K + (size_t)n0 * 3072, 3072, 3072, 16, As, Bs, acc);
  bf16* Sb = S + (size_t)b * 2048 * 2048;
  EPILOGUE32(Sb[row * 2048 + col] = (bf16)val);
}

// ---------------------------------------------------------------------------
// Kernel 5: masked softmax per row, in place (S -> P). Loads below len,
// stores below kmax = ceil64(len), zeros on [len, kmax).
// ---------------------------------------------------------------------------
__global__ __launch_bounds__(256) void k_softmax(bf16* __restrict__ S,
                                                 const int* __restrict__ lens) {
  const int row = blockIdx.x;  // 0..16383 (= b*2048 + q)
  const int len = lens[row >> 11];
  const int kmax = (len + 63) & ~63;
  bf16* Sr = S + (size_t)row * 2048;
  const int tid = threadIdx.x;
  const int base = tid * 8;
  __shared__ float red[4];

  float f[8];
  if (base < len) {
    bf16x8 v = ((const bf16x8*)Sr)[tid];
#pragma unroll
    for (int e = 0; e < 8; ++e) f[e] = (base + e < len) ? (float)v[e] : -1e30f;
  } else {
#pragma unroll
    for (int e = 0; e < 8; ++e) f[e] = -1e30f;
  }
  float m = -1e30f;
#pragma unroll
  for (int e = 0; e < 8; ++e) m = fmaxf(m, f[e]);
#pragma unroll
  for (int off = 32; off; off >>= 1) m = fmaxf(m, __shfl_xor(m, off));
  if ((tid & 63) == 0) red[tid >> 6] = m;
  __syncthreads();
  m = fmaxf(fmaxf(red[0], red[1]), fmaxf(red[2], red[3]));
  __syncthreads();

  float s = 0.f;
#pragma unroll
  for (int e = 0; e < 8; ++e) {
    float p = (base + e < len) ? __expf(f[e] - m) : 0.f;
    f[e] = p;
    s += p;
  }
#pragma unroll
  for (int off = 32; off; off >>= 1) s += __shfl_xor(s, off);
  if ((tid & 63) == 0) red[tid >> 6] = s;
  __syncthreads();
  s = red[0] + red[1] + red[2] + red[3];
  const float inv = 1.f / s;

  if (base < kmax) {
    bf16x8 o;
#pragma unroll
    for (int e = 0; e < 8; ++e) o[e] = (bf16)(f[e] * inv);
    ((bf16x8*)Sr)[tid] = o;
  }
}

// ---------------------------------------------------------------------------
// Kernel 6: O = P @ Vt^T per batch (M=2048, N=1024, K=ceil(len,64)), fp32.
// 32x32x16 path (same rationale as scores).
// ---------------------------------------------------------------------------
__global__ __launch_bounds__(256) void k_gemm_out(const bf16* __restrict__ P,
                                                  const bf16* __restrict__ Vt,
                                                  const int* __restrict__ lens,
                                                  float* __restrict__ Out) {
  const int b = blockIdx.z;
  const int kTiles = (lens[b] + 63) >> 6;  // P is zero beyond len within tile
  const int n0 = blockIdx.x * 128;  // over d (1024)
  const int m0 = blockIdx.y * 128;  // over queries
  __shared__ __align__(16) bf16 As[128 * 64];
  __shared__ __align__(16) bf16 Bs[128 * 64];
  const bf16* Pb = P + (size_t)b * 2048 * 2048;
  const bf16* Vb = Vt + (size_t)b * 1024 * 2048;
  f32x16 acc[2][2] = {};
  gemm_tile32(Pb + (size_t)m0 * 2048, Vb + (size_t)n0 * 2048, 2048, 2048, kTiles, As, Bs, acc);
  float* Ob = Out + (size_t)b * 2048 * 1024;
  EPILOGUE32(Ob[row * 1024 + col] = val);
}

// ---------------------------------------------------------------------------
// Workspace layout (bytes):
//   [0,   32M)   Xb   (dead after GEMM1)  \ overlapped by
//   [32M, 38M)   Wb   (dead after GEMM1)  /  S/P: [0, 64M)
//   [64M, 160M)  QKV  bf16 [16384][3072]
//   [160M,192M)  Vt   bf16 [8][1024][2048]
// ---------------------------------------------------------------------------
extern "C" void kernel_launch(void* const* d_in, const int* in_sizes, int n_in,
                              void* d_out, int out_size, void* d_ws, size_t ws_size,
                              hipStream_t stream) {
  const float* x   = (const float*)d_in[0];
  const int* lens  = (const int*)d_in[1];
  const float* Wq  = (const float*)d_in[2];
  const float* Wk  = (const float*)d_in[3];
  const float* Wv  = (const float*)d_in[4];
  float* out = (float*)d_out;

  char* ws = (char*)d_ws;
  bf16* S   = (bf16*)(ws);                 // 64 MiB (scores, then P in place)
  bf16* Xb  = (bf16*)(ws);                 // 32 MiB, overlaps S (dead first)
  bf16* Wb  = (bf16*)(ws + 33554432);      // 6 MiB, overlaps S
  bf16* QKV = (bf16*)(ws + 67108864);      // 96 MiB
  bf16* Vt  = (bf16*)(ws + 167772160);     // 32 MiB

  k_cast_all<<<19456, 256, 0, stream>>>(x, Wq, Wk, Wv, Xb, Wb);
  k_gemm_qkv<<<dim3(24, 128), 256, 0, stream>>>(Xb, Wb, lens, QKV);
  k_transpose_v<<<dim3(64, 32, 8), dim3(32, 8), 0, stream>>>(QKV, lens, Vt);
  k_gemm_scores<<<dim3(16, 16, 8), 256, 0, stream>>>(QKV, lens, S);
  k_softmax<<<16384, 256, 0, stream>>>(S, lens);
  k_gemm_out<<<dim3(8, 16, 8), 256, 0, stream>>>(S, Vt, lens, out);
}